// Round 12
// baseline (600.827 us; speedup 1.0000x reference)
//
#include <hip/hip_runtime.h>
#include <hip/hip_bf16.h>
#include <stdint.h>

// KVMemoryLayer: scores = x@keys^T (512x200000, K=1024 fp32), top-32/row,
// softmax, weighted gather of vals.
// R12: R11 geometry (BM=512, BN=64, grid 3125, keys read once) with the
//     staging rebuilt around the fat-block's tiny per-thread footprint:
//     - A LDS eliminated: MFMA A-fragments are direct 16B global loads from
//       L2-resident xb (wave reads only its own 32 rows), double-set
//       prefetched one half-step ahead (32 VGPR).
//     - B 2-deep register prefetch (breg0/breg1 = 8 VGPR): writeB(t) waits
//       on a load issued 2 steps (~2000cy) earlier >= HBM latency. This is
//       the R5/R7 idea, now affordable (they spilled at 24-48 regs/set).
//     - LDS 11KB (was 85KB); barrier region = 8KB B write only.
//     Reg budget: acc32 + A32 + B8 + addr ~= 90 < 128 of (1024,4) -> no spill.

#define KTOP 32
#define MROWS 512
#define NKEYS 200000
#define DDIM 1024

#define BN2 64
#define BK 64
#define LDT 72          // padded LDS row length in bf16 elems (144 B)
#define NSTEP 16        // DDIM/BK
#define NCOLT2 3125     // 200000/64 exactly
#define NT2 3136        // padded (mult of 8, uint4-clean)
#define TCAP 512
#define CCAP 256
#define TMARGIN 0.125f  // >> 2*bf16-gemm error (~0.004); provable coverage

typedef __attribute__((ext_vector_type(4))) float f32x4;
typedef __attribute__((ext_vector_type(8))) short short8;

__device__ __forceinline__ unsigned short f2bf(float f) {      // hw RNE cvt
    __hip_bfloat16 h = __float2bfloat16(f);
    return *reinterpret_cast<unsigned short*>(&h);
}
__device__ __forceinline__ int enc16(unsigned short u) {       // monotone order-encode
    return (int)(u ^ ((u & 0x8000u) ? 0xFFFFu : 0x8000u));
}
__device__ __forceinline__ float dec_enc(int e) {              // encoded -> float
    unsigned short u = (unsigned short)((e & 0x8000) ? (e ^ 0x8000) : (e ^ 0xFFFF));
    return __uint_as_float((unsigned int)u << 16);
}
__device__ __forceinline__ float bf2f(unsigned short u) {
    return __uint_as_float((unsigned int)u << 16);
}

// ---------------------------------------------------------------- cvt x->bf16
__global__ void cvt_x_kernel(const float* __restrict__ x, unsigned short* __restrict__ xb) {
    int i = blockIdx.x * blockDim.x + threadIdx.x;      // 131072 threads, 4 elems each
    f32x4 v = reinterpret_cast<const f32x4*>(x)[i];
    ushort4 o;
    o.x = f2bf(v.x); o.y = f2bf(v.y); o.z = f2bf(v.z); o.w = f2bf(v.w);
    reinterpret_cast<ushort4*>(xb)[i] = o;
}

// ---------------------------------------------------------------- K1: scores
// 1024 threads = 16 waves; wave w owns rows [w*32, w*32+32) x all 64 cols.
__global__ __launch_bounds__(1024, 4)
void score_gemm(const float* __restrict__ keys, const unsigned short* __restrict__ xb,
                unsigned short* __restrict__ scores, unsigned short* __restrict__ tilemax) {
    __shared__ unsigned short Bs[BN2 * LDT];     //  9216 B (single buffer)
    __shared__ int tmax[MROWS];                  //  2048 B

    const int tid  = threadIdx.x;
    const int lane = tid & 63;
    const int w    = tid >> 6;          // wave 0..15

    const int g    = blockIdx.x;        // col tile 0..3124
    const int col0 = g * BN2;

    if (tid < MROWS) tmax[tid] = 0;     // enc 0 < any real finite score's enc

    f32x4 acc[2][4];                    // 32 regs/lane
#pragma unroll
    for (int m = 0; m < 2; m++)
#pragma unroll
        for (int n = 0; n < 4; n++) acc[m][n] = (f32x4){0.f, 0.f, 0.f, 0.f};

    const int rl = lane & 15;
    const int kl = (lane >> 4) * 8;

    // A fragment bases: lane's own rows (w*32 + m*16 + rl), k-slice kl
    const unsigned short* Arow0 = xb + (size_t)(w * 32 + rl) * DDIM + kl;
    const unsigned short* Arow1 = Arow0 + 16 * DDIM;

    short8 af0[2][2], af1[2][2];        // two A fragment sets (16+16 regs)
    f32x4  breg0, breg1;                // two B staging sets (4+4 regs)

    auto loadA = [&](short8 (&af)[2][2], int t) {
        const int k0 = t * BK;
        af[0][0] = *reinterpret_cast<const short8*>(Arow0 + k0);
        af[0][1] = *reinterpret_cast<const short8*>(Arow0 + k0 + 32);
        af[1][0] = *reinterpret_cast<const short8*>(Arow1 + k0);
        af[1][1] = *reinterpret_cast<const short8*>(Arow1 + k0 + 32);
    };
    const int br = tid >> 4, bj = tid & 15;        // B: 64 rows x 16 f32x4-chunks
    auto loadB = [&](f32x4& br_, int t) {
        br_ = *reinterpret_cast<const f32x4*>(keys + (size_t)(col0 + br) * DDIM + t * BK + bj * 4);
    };
    auto writeB = [&](const f32x4& v) {
        ushort4 o;
        o.x = f2bf(v.x); o.y = f2bf(v.y);
        o.z = f2bf(v.z); o.w = f2bf(v.w);
        *reinterpret_cast<ushort4*>(&Bs[br * LDT + bj * 4]) = o;
    };
    auto compute = [&](short8 (&af)[2][2]) {
#pragma unroll
        for (int kki = 0; kki < 2; kki++) {
            short8 bf[4];
#pragma unroll
            for (int n = 0; n < 4; n++)
                bf[n] = *reinterpret_cast<const short8*>(&Bs[(n * 16 + rl) * LDT + kl + kki * 32]);
#pragma unroll
            for (int m = 0; m < 2; m++)
#pragma unroll
                for (int n = 0; n < 4; n++)
                    acc[m][n] = __builtin_amdgcn_mfma_f32_16x16x32_bf16(af[m][kki], bf[n], acc[m][n], 0, 0, 0);
        }
    };

    // prologue: B(0),B(1) in flight (2-deep); A(0) in flight
    loadB(breg0, 0); loadB(breg1, 1);
    loadA(af0, 0);

    for (int t = 0; t < NSTEP; t += 2) {
        // even half-step: B(t) from breg0
        __syncthreads();                         // prev compute done reading Bs
        writeB(breg0);                           // waits (counted) on breg0 only
        __syncthreads();
        if (t + 2 < NSTEP) loadB(breg0, t + 2);  // 2 steps ahead
        loadA(af1, t + 1);                       // half-step ahead (L2)
        compute(af0);
        // odd half-step: B(t+1) from breg1
        __syncthreads();
        writeB(breg1);
        __syncthreads();
        if (t + 3 < NSTEP) loadB(breg1, t + 3);
        if (t + 2 < NSTEP) loadA(af0, t + 2);
        compute(af1);
    }

    // epilogue: store bf16 scores + per-(row,tile) max (no OOB: 200000=64*3125)
    const int rg = lane >> 4;
#pragma unroll
    for (int m = 0; m < 2; m++) {
#pragma unroll
        for (int j = 0; j < 4; j++) {
            int lrow = w * 32 + m * 16 + rg * 4 + j;
            float mx = -1e30f;
#pragma unroll
            for (int n = 0; n < 4; n++) {
                float v = acc[m][n][j];
                mx = fmaxf(mx, v);
                scores[(size_t)lrow * NKEYS + col0 + n * 16 + rl] = f2bf(v);
            }
#pragma unroll
            for (int sft = 1; sft < 16; sft <<= 1) mx = fmaxf(mx, __shfl_xor(mx, sft));
            if (rl == 0)
                atomicMax(&tmax[lrow], enc16(f2bf(mx)));
        }
    }
    __syncthreads();
    if (tid < MROWS)
        tilemax[(size_t)tid * NT2 + g] = (unsigned short)tmax[tid];
}

// ------------------------------------------------- K2: select+refine+output
__global__ __launch_bounds__(256)
void select_kernel(const float* __restrict__ x, const float* __restrict__ keys,
                   const float* __restrict__ vals, const unsigned short* __restrict__ scores,
                   const unsigned short* __restrict__ tilemax, float* __restrict__ out) {
    const int n    = blockIdx.x;
    const int tid  = threadIdx.x;
    const int lane = tid & 63;
    const int w    = tid >> 6;

    __shared__ __align__(16) float qs[DDIM];
    __shared__ unsigned short enc_t[NT2];
    __shared__ int    hist[256];
    __shared__ int    tiles[TCAP];
    __shared__ int    cand[CCAP];
    __shared__ double rsc[CCAP];
    __shared__ float  wgt[KTOP];
    __shared__ int    topslot[KTOP];
    __shared__ float  topval[KTOP];
    __shared__ int    ntiles, ncand, sbsel, sabove, st32e;

    reinterpret_cast<f32x4*>(qs)[tid] = reinterpret_cast<const f32x4*>(x + (size_t)n * DDIM)[tid];
    hist[tid] = 0;
    if (tid < 32) { wgt[tid] = 0.f; topslot[tid] = -1; }
    if (tid == 0) { ntiles = 0; ncand = 0; }
    // load tile-max row (encoded bf16); phantom tiles (>=NCOLT2) forced to 0
    for (int i = tid; i < NT2; i += 256)
        enc_t[i] = (i < NCOLT2) ? tilemax[(size_t)n * NT2 + i] : 0;
    __syncthreads();

    // --- exact 32nd-largest tile-max via two-level 8-bit radix ---
    for (int i = tid; i < NT2; i += 256) atomicAdd(&hist[enc_t[i] >> 8], 1);
    __syncthreads();
    if (tid == 0) {
        int cum = 0, b = 255;
        for (; b >= 0; b--) { cum += hist[b]; if (cum >= KTOP) break; }
        sbsel = b; sabove = cum - hist[b];
    }
    __syncthreads();
    const int bsel = sbsel;
    hist[tid] = 0;
    __syncthreads();
    for (int i = tid; i < NT2; i += 256) {
        int e = enc_t[i];
        if ((e >> 8) == bsel) atomicAdd(&hist[e & 0xFF], 1);
    }
    __syncthreads();
    if (tid == 0) {
        int cum = sabove, lb = 255;
        for (; lb >= 0; lb--) { cum += hist[lb]; if (cum >= KTOP) break; }
        st32e = (bsel << 8) | lb;
    }
    __syncthreads();
    const float thr = dec_enc(st32e) - TMARGIN;   // covers exact top-32

    // --- select tiles with max >= thr ---
    for (int i = tid; i < NT2; i += 256) {
        if (dec_enc(enc_t[i]) >= thr) {
            int p = atomicAdd(&ntiles, 1);
            if (p < TCAP) tiles[p] = i;
        }
    }
    __syncthreads();
    const int nt = ntiles < TCAP ? ntiles : TCAP;

    // --- scan selected tiles (64 cols each), collect candidates >= thr ---
    for (int idx = tid; idx < nt * BN2; idx += 256) {
        int col = tiles[idx >> 6] * BN2 + (idx & 63);
        float v = bf2f(scores[(size_t)n * NKEYS + col]);
        if (v >= thr) {
            int p = atomicAdd(&ncand, 1);
            if (p < CCAP) cand[p] = col;
        }
    }
    __syncthreads();
    const int cnt = ncand < CCAP ? ncand : CCAP;

    // --- refine: exact dot(x_row, keys[cand]) with f64 accum, one wave/cand ---
    for (int ci = w; ci < cnt; ci += 4) {
        const f32x4* kv = reinterpret_cast<const f32x4*>(keys + (size_t)cand[ci] * DDIM) + lane * 4;
        const f32x4* qv = reinterpret_cast<const f32x4*>(qs) + lane * 4;
        double a = 0.0;
#pragma unroll
        for (int i = 0; i < 4; i++) {
            f32x4 q = qv[i], k = kv[i];
            a += (double)q.x * k.x + (double)q.y * k.y + (double)q.z * k.z + (double)q.w * k.w;
        }
#pragma unroll
        for (int sft = 32; sft >= 1; sft >>= 1) a += __shfl_xor(a, sft);
        if (lane == 0) rsc[ci] = a;
    }
    __syncthreads();

    // --- exact top-32 among candidates (wave 0) ---
    if (w == 0) {
        double v0[4]; int id0[4];
#pragma unroll
        for (int sft = 0; sft < 4; sft++) {
            int p = lane + sft * 64;
            if (p < cnt) { v0[sft] = rsc[p]; id0[sft] = p; } else { v0[sft] = -1e300; id0[sft] = -1; }
        }
        for (int k = 0; k < KTOP; k++) {
            double bv = v0[0]; int bi = id0[0];
#pragma unroll
            for (int sft = 1; sft < 4; sft++) if (v0[sft] > bv) { bv = v0[sft]; bi = id0[sft]; }
#pragma unroll
            for (int sft = 32; sft >= 1; sft >>= 1) {
                double ov = __shfl_xor(bv, sft);
                int    oi = __shfl_xor(bi, sft);
                if (ov > bv) { bv = ov; bi = oi; }
            }
            if (lane == 0) { topslot[k] = bi; topval[k] = (float)bv; }
#pragma unroll
            for (int sft = 0; sft < 4; sft++) if (bi >= 0 && id0[sft] == bi) v0[sft] = -1e300;
        }
    }
    __syncthreads();

    // --- softmax over the 32 exact scores ---
    if (tid == 0) {
        float mx = topval[0];
        float sum = 0.f;
        for (int k = 0; k < KTOP; k++) {
            float e = (topslot[k] >= 0) ? expf(topval[k] - mx) : 0.f;
            wgt[k] = e; sum += e;
        }
        float inv = 1.f / sum;
        for (int k = 0; k < KTOP; k++) wgt[k] *= inv;
    }
    __syncthreads();

    // --- output: weighted sum of selected vals rows ---
    f32x4 accv = (f32x4){0.f, 0.f, 0.f, 0.f};
    for (int k = 0; k < KTOP; k++) {
        int sl = topslot[k];
        if (sl >= 0) {
            float wk = wgt[k];
            f32x4 v = reinterpret_cast<const f32x4*>(vals + (size_t)cand[sl] * DDIM)[tid];
            accv.x += wk * v.x; accv.y += wk * v.y; accv.z += wk * v.z; accv.w += wk * v.w;
        }
    }
    reinterpret_cast<f32x4*>(out + (size_t)n * DDIM)[tid] = accv;
}

// ---------------------------------------------------------------- launch
extern "C" void kernel_launch(void* const* d_in, const int* in_sizes, int n_in,
                              void* d_out, int out_size, void* d_ws, size_t ws_size,
                              hipStream_t stream) {
    const float* x    = (const float*)d_in[0];
    const float* keys = (const float*)d_in[1];
    const float* vals = (const float*)d_in[2];
    float* out = (float*)d_out;

    char* ws = (char*)d_ws;
    unsigned short* scores  = (unsigned short*)ws;                         // 204,800,000 B
    unsigned short* xb      = (unsigned short*)(ws + 204800000);           //   1,048,576 B
    unsigned short* tilemax = (unsigned short*)(ws + 204800000 + 1048576); //   3,211,264 B

    cvt_x_kernel<<<512, 256, 0, stream>>>(x, xb);
    score_gemm<<<NCOLT2, 1024, 0, stream>>>(keys, xb, scores, tilemax);
    select_kernel<<<MROWS, 256, 0, stream>>>(x, keys, vals, scores, tilemax, out);
}